// Round 9
// baseline (189.309 us; speedup 1.0000x reference)
//
#include <hip/hip_runtime.h>
#include <hip/hip_bf16.h>
#include <math.h>

#define HID 4096
#define R_TOTAL 16384

typedef __attribute__((ext_vector_type(8))) short short8;
typedef __attribute__((ext_vector_type(8))) unsigned short ushort8;
typedef __attribute__((ext_vector_type(4))) float f32x4;

__device__ __forceinline__ ushort bfc(float f) {
  __hip_bfloat16 h = __float2bfloat16(f);
  return *(ushort*)&h;
}

// ---------------------------------------------------------------------------
// Prep: w1T bf16 [32][4096], w4T bf16 [4096][32], coupled[16] -> cpl[0..15],
// and gacc zeroing (folded in; prep precedes phase1 on the same stream).
// ---------------------------------------------------------------------------
__global__ __launch_bounds__(256) void wn_prep(
    const float* __restrict__ w1, const float* __restrict__ w4,
    ushort* __restrict__ w1T, ushort* __restrict__ w4T,
    const float* __restrict__ freq, const float* __restrict__ phases,
    const float* __restrict__ coupling, const float* __restrict__ damping,
    const float* __restrict__ tstep, float* __restrict__ cpl,
    float* __restrict__ gacc)
{
  __shared__ ushort tile[64*72];
  __shared__ float base[16];
  const int b = blockIdx.x, t = threadIdx.x;
  if (b < 64) {                      // w1T chunk: k in [b*64, b*64+64)
    #pragma unroll
    for (int i = 0; i < 8; ++i) {
      const int e = t + i*256, kk = e >> 5, c = e & 31;
      tile[c*72 + kk] = bfc(w1[(size_t)(b*64+kk)*32 + c]);
    }
    __syncthreads();
    const int c = t >> 3, j = t & 7;
    ushort8 v;
    #pragma unroll
    for (int q = 0; q < 8; ++q) v[q] = tile[c*72 + j*8 + q];
    *(ushort8*)&w1T[(size_t)c*HID + b*64 + j*8] = v;
  } else if (b < 128) {              // w4T chunk: h in [b2*64, b2*64+64)
    const int b2 = b - 64;
    #pragma unroll
    for (int i = 0; i < 8; ++i) {
      const int e = t + i*256, d = e >> 6, hh = e & 63;
      tile[hh*40 + d] = bfc(w4[(size_t)d*HID + b2*64 + hh]);
    }
    __syncthreads();
    const int hh = t >> 2, j = t & 3;
    ushort8 v;
    #pragma unroll
    for (int q = 0; q < 8; ++q) v[q] = tile[hh*40 + j*8 + q];
    *(ushort8*)&w4T[(size_t)(b2*64+hh)*32 + j*8] = v;
  } else {                           // coupled + gacc zero
    const float tt = tstep[0] + 0.1f;
    if (t < 16) {
      gacc[t] = 0.f;
      base[t] = sinf(6.283185307179586f*freq[t]*tt + phases[t]) * expf(-damping[t]*tt);
    }
    __syncthreads();
    if (t < 16) {
      float s = 0.f;
      #pragma unroll
      for (int i = 0; i < 16; ++i) s += base[i]*coupling[i*16+t];
      cpl[t] = tanhf(s);
    }
  }
}

// ---------------------------------------------------------------------------
// Phase 1 (bf16-LDS MFMA, R8 version): x@w1 -> LN -> SiLU -> @w2 -> mod -> @w3
//   -> LN -> SiLU -> o(bf16).
// 512 blocks x 256 thr (4 waves), 32 rows/block; waves = 2 m-tiles x split-K/2.
// x converted to bf16 AT STAGING, granule-XOR swizzled LDS, double-buffered.
// ---------------------------------------------------------------------------
__global__ __launch_bounds__(256) void wn_phase1(
    const float* __restrict__ x, const ushort* __restrict__ w1T,
    const float* __restrict__ b1, const float* __restrict__ g1,
    const float* __restrict__ beta1, const float* __restrict__ w2,
    const float* __restrict__ b2, const float* __restrict__ w3,
    const float* __restrict__ b3, const float* __restrict__ g2,
    const float* __restrict__ beta2, const float* __restrict__ cpl,
    ushort* __restrict__ o_ws, float* __restrict__ gacc)
{
  __shared__ __align__(16) float lds[6720];
  ushort* xb  = (ushort*)lds;      // 2 x [32 rows][16 granules x 8 bf16] (16KB)
  float* red  = lds;               // overlay after K-loop: [2][32][33] = 2112
  float* yl   = lds + 4096;        // [32][33]
  float* w2l  = lds + 5152;        // [32][16]
  float* w3l  = lds + 5664;        // [16][32]
  float* msum = lds + 6176;        // [32][17]
  const int t  = threadIdx.x;
  const int r0 = blockIdx.x * 32;

  if (t < 128) *(float4*)&w2l[t*4] = *(const float4*)&w2[t*4];
  else { const int u2 = t-128; *(float4*)&w3l[u2*4] = *(const float4*)&w3[u2*4]; }

  const int srow = t >> 3, sc = t & 7;
  const int wg0   = ((sc*2) ^ ((srow&7)<<1));
  const int wbase = srow*128 + wg0*8;
  const float* xp = &x[(size_t)(r0+srow)*HID + sc*16];

  const int w    = t >> 6, l = t & 63;
  const int mt   = w & 1, kh = w >> 1;
  const int lrow = l & 15, lkb = l >> 4;
  const int arow = mt*16 + lrow;
  const int rsw  = (arow&7) << 1;
  const int ra_s0 = arow*128 + ((kh*8 +     lkb) ^ rsw)*8;
  const int ra_s1 = arow*128 + ((kh*8 + 4 + lkb) ^ rsw)*8;
  const ushort* bp0 = &w1T[(size_t)lrow*HID + kh*64 + lkb*8];
  const ushort* bp1 = bp0 + 16*HID;

  f32x4 acc0 = {0.f,0.f,0.f,0.f}, acc1 = {0.f,0.f,0.f,0.f};
  float4 rg0, rg1, rg2, rg3;

  rg0 = *(const float4*)&xp[0];
  rg1 = *(const float4*)&xp[4];
  rg2 = *(const float4*)&xp[8];
  rg3 = *(const float4*)&xp[12];
  {
    ushort8 v0, v1;
    v0[0]=bfc(rg0.x); v0[1]=bfc(rg0.y); v0[2]=bfc(rg0.z); v0[3]=bfc(rg0.w);
    v0[4]=bfc(rg1.x); v0[5]=bfc(rg1.y); v0[6]=bfc(rg1.z); v0[7]=bfc(rg1.w);
    v1[0]=bfc(rg2.x); v1[1]=bfc(rg2.y); v1[2]=bfc(rg2.z); v1[3]=bfc(rg2.w);
    v1[4]=bfc(rg3.x); v1[5]=bfc(rg3.y); v1[6]=bfc(rg3.z); v1[7]=bfc(rg3.w);
    *(ushort8*)&xb[wbase]     = v0;
    *(ushort8*)&xb[wbase + 8] = v1;
  }

  for (int it = 0; it < 32; ++it) {
    const int cur = it & 1;
    if (it < 31) {
      const int kc = (it+1)*128;
      rg0 = *(const float4*)&xp[kc];
      rg1 = *(const float4*)&xp[kc + 4];
      rg2 = *(const float4*)&xp[kc + 8];
      rg3 = *(const float4*)&xp[kc + 12];
    }
    __syncthreads();
    {
      const ushort* xc = &xb[cur*4096];
      const int kg = it*128;
      const short8 av0 = *(const short8*)&xc[ra_s0];
      const short8 bv00 = *(const short8*)(bp0 + kg);
      const short8 bv01 = *(const short8*)(bp1 + kg);
      acc0 = __builtin_amdgcn_mfma_f32_16x16x32_bf16(av0, bv00, acc0, 0, 0, 0);
      acc1 = __builtin_amdgcn_mfma_f32_16x16x32_bf16(av0, bv01, acc1, 0, 0, 0);
      const short8 av1 = *(const short8*)&xc[ra_s1];
      const short8 bv10 = *(const short8*)(bp0 + kg + 32);
      const short8 bv11 = *(const short8*)(bp1 + kg + 32);
      acc0 = __builtin_amdgcn_mfma_f32_16x16x32_bf16(av1, bv10, acc0, 0, 0, 0);
      acc1 = __builtin_amdgcn_mfma_f32_16x16x32_bf16(av1, bv11, acc1, 0, 0, 0);
    }
    __syncthreads();
    if (it < 31) {
      ushort* xn = &xb[(cur^1)*4096];
      ushort8 v0, v1;
      v0[0]=bfc(rg0.x); v0[1]=bfc(rg0.y); v0[2]=bfc(rg0.z); v0[3]=bfc(rg0.w);
      v0[4]=bfc(rg1.x); v0[5]=bfc(rg1.y); v0[6]=bfc(rg1.z); v0[7]=bfc(rg1.w);
      v1[0]=bfc(rg2.x); v1[1]=bfc(rg2.y); v1[2]=bfc(rg2.z); v1[3]=bfc(rg2.w);
      v1[4]=bfc(rg3.x); v1[5]=bfc(rg3.y); v1[6]=bfc(rg3.z); v1[7]=bfc(rg3.w);
      *(ushort8*)&xn[wbase]     = v0;
      *(ushort8*)&xn[wbase + 8] = v1;
    }
  }
  __syncthreads();
  #pragma unroll
  for (int j = 0; j < 4; ++j) {
    red[kh*1056 + (mt*16 + lkb*4 + j)*33 + lrow]      = acc0[j];
    red[kh*1056 + (mt*16 + lkb*4 + j)*33 + 16 + lrow] = acc1[j];
  }
  __syncthreads();
  #pragma unroll
  for (int i = 0; i < 4; ++i) {
    const int e = t + i*256, row = e >> 5, col = e & 31;
    yl[row*33+col] = red[row*33+col] + red[1056 + row*33+col];
  }
  __syncthreads();
  if (t < 128) {
    const int row = t >> 2, q = t & 3, d0 = q*8;
    float v[8]; float mu = 0.f;
    #pragma unroll
    for (int dd = 0; dd < 8; ++dd) { v[dd] = yl[row*33 + d0+dd] + b1[d0+dd]; mu += v[dd]; }
    mu += __shfl_xor(mu,1); mu += __shfl_xor(mu,2); mu *= (1.f/32.f);
    float var = 0.f;
    #pragma unroll
    for (int dd = 0; dd < 8; ++dd) { const float c = v[dd]-mu; var += c*c; }
    var += __shfl_xor(var,1); var += __shfl_xor(var,2);
    const float rs = rsqrtf(var*(1.f/32.f) + 1e-5f);
    float wiv[16];
    #pragma unroll
    for (int ww = 0; ww < 16; ++ww) wiv[ww] = 0.f;
    #pragma unroll
    for (int dd = 0; dd < 8; ++dd) {
      const float hn = (v[dd]-mu)*rs*g1[d0+dd] + beta1[d0+dd];
      const float sl = hn / (1.f + __expf(-hn));
      const float* wr = &w2l[(d0+dd)*16];
      #pragma unroll
      for (int ww = 0; ww < 16; ++ww) wiv[ww] = fmaf(sl, wr[ww], wiv[ww]);
    }
    #pragma unroll
    for (int ww = 0; ww < 16; ++ww) {
      wiv[ww] += __shfl_xor(wiv[ww],1);
      wiv[ww] += __shfl_xor(wiv[ww],2);
    }
    float mod[16];
    #pragma unroll
    for (int ww = 0; ww < 16; ++ww) mod[ww] = cpl[ww]*(1.f + wiv[ww] + b2[ww]);
    #pragma unroll
    for (int j = 0; j < 4; ++j) msum[row*17 + q*4+j] = mod[q*4+j];
    float p[8];
    #pragma unroll
    for (int dd = 0; dd < 8; ++dd) p[dd] = b3[d0+dd];
    #pragma unroll
    for (int ww = 0; ww < 16; ++ww) {
      const float m = mod[ww];
      const float* wr = &w3l[ww*32 + d0];
      #pragma unroll
      for (int dd = 0; dd < 8; ++dd) p[dd] = fmaf(m, wr[dd], p[dd]);
    }
    float mu2 = 0.f;
    #pragma unroll
    for (int dd = 0; dd < 8; ++dd) mu2 += p[dd];
    mu2 += __shfl_xor(mu2,1); mu2 += __shfl_xor(mu2,2); mu2 *= (1.f/32.f);
    float var2 = 0.f;
    #pragma unroll
    for (int dd = 0; dd < 8; ++dd) { const float c = p[dd]-mu2; var2 += c*c; }
    var2 += __shfl_xor(var2,1); var2 += __shfl_xor(var2,2);
    const float rs2 = rsqrtf(var2*(1.f/32.f) + 1e-5f);
    ushort8 ov;
    #pragma unroll
    for (int dd = 0; dd < 8; ++dd) {
      const float hn = (p[dd]-mu2)*rs2*g2[d0+dd] + beta2[d0+dd];
      ov[dd] = bfc(hn / (1.f + __expf(-hn)));
    }
    *(ushort8*)&o_ws[(size_t)(r0+row)*32 + d0] = ov;
  }
  __syncthreads();
  if (t < 16) {
    float s = 0.f;
    for (int r = 0; r < 32; ++r) s += msum[r*17 + t];
    atomicAdd(gacc + t, s);
  }
}

// ---------------------------------------------------------------------------
// Phase 2: resonance_factor -> cpl[16]
// ---------------------------------------------------------------------------
__global__ void wn_phase2(const float* __restrict__ gacc, float* __restrict__ cpl)
{
  __shared__ float res[16];
  const int t = threadIdx.x;
  if (t < 16) res[t] = 0.1f * fabsf(gacc[t] * (1.f/(float)R_TOTAL));
  __syncthreads();
  if (t == 0) {
    float s = 0.f;
    #pragma unroll
    for (int ww = 0; ww < 16; ++ww) s += res[ww];
    cpl[16] = 1.f / (1.f + expf(-s*(1.f/16.f)));
  }
}

// ---------------------------------------------------------------------------
// Phase 3 v5 (2 m-tiles/wave sharing one w4T A-frag): out = x + rf*(o@w4+b4).
// Halves w4T request rate; doubles x/out ILP with NAMED regs. Reversed row
// order (harvest phase1's L3-resident x tail), nt stores, plain x loads.
// 1024 blocks (128 row-blks of 128 rows x 8 strips) x 256 thr (4 waves).
// ---------------------------------------------------------------------------
__global__ __launch_bounds__(256) void wn_phase3(
    const float* __restrict__ x, const ushort* __restrict__ o_bf,
    const ushort* __restrict__ w4T, const float* __restrict__ b4,
    const float* __restrict__ cpl, float* __restrict__ out)
{
  const int t = threadIdx.x, l = t & 63, w = t >> 6;
  const int bid = blockIdx.x;
  const int strip = bid & 7;
  const int m0 = (127 - (bid >> 3)) * 128 + w*32;   // reversed row order
  const float rf = cpl[16];
  const int lm = l & 15, lkb = l >> 4;
  // B-frags for the two m-tiles (o rows = col operand)
  const short8 bv0 = *(const short8*)&o_bf[(size_t)(m0+lm)*32 + lkb*8];
  const short8 bv1 = *(const short8*)&o_bf[(size_t)(m0+16+lm)*32 + lkb*8];
  const size_t rowbase0 = (size_t)(m0+lm)*HID + strip*512 + lkb*4;
  const size_t rowbase1 = rowbase0 + (size_t)16*HID;
  const ushort* wp = &w4T[(size_t)(strip*512 + lm)*32 + lkb*8];
  const float* b4p = &b4[strip*512 + lkb*4];

  #pragma unroll 2
  for (int nt = 0; nt < 32; ++nt) {
    const int nb = nt*16;
    // shared A-frag (w4T rows = row operand)
    const short8 av = *(const short8*)(wp + (size_t)nb*32);
    const float4 xv0 = *(const float4*)&x[rowbase0 + nb];
    const float4 xv1 = *(const float4*)&x[rowbase1 + nb];
    const float4 b4v = *(const float4*)&b4p[nb];
    f32x4 c0 = {0.f,0.f,0.f,0.f}, c1 = {0.f,0.f,0.f,0.f};
    c0 = __builtin_amdgcn_mfma_f32_16x16x32_bf16(av, bv0, c0, 0, 0, 0);
    c1 = __builtin_amdgcn_mfma_f32_16x16x32_bf16(av, bv1, c1, 0, 0, 0);
    f32x4 s0, s1;
    s0[0] = fmaf(rf, c0[0] + b4v.x, xv0.x);
    s0[1] = fmaf(rf, c0[1] + b4v.y, xv0.y);
    s0[2] = fmaf(rf, c0[2] + b4v.z, xv0.z);
    s0[3] = fmaf(rf, c0[3] + b4v.w, xv0.w);
    s1[0] = fmaf(rf, c1[0] + b4v.x, xv1.x);
    s1[1] = fmaf(rf, c1[1] + b4v.y, xv1.y);
    s1[2] = fmaf(rf, c1[2] + b4v.z, xv1.z);
    s1[3] = fmaf(rf, c1[3] + b4v.w, xv1.w);
    __builtin_nontemporal_store(s0, (f32x4*)&out[rowbase0 + nb]);
    __builtin_nontemporal_store(s1, (f32x4*)&out[rowbase1 + nb]);
  }
}

extern "C" void kernel_launch(void* const* d_in, const int* in_sizes, int n_in,
                              void* d_out, int out_size, void* d_ws, size_t ws_size,
                              hipStream_t stream) {
  const float* x        = (const float*)d_in[0];
  const float* freq     = (const float*)d_in[1];
  const float* phases   = (const float*)d_in[2];
  const float* coupling = (const float*)d_in[3];
  const float* damping  = (const float*)d_in[4];
  const float* w1       = (const float*)d_in[5];
  const float* b1       = (const float*)d_in[6];
  const float* g1       = (const float*)d_in[7];
  const float* beta1    = (const float*)d_in[8];
  const float* w2       = (const float*)d_in[9];
  const float* b2       = (const float*)d_in[10];
  const float* w3       = (const float*)d_in[11];
  const float* b3       = (const float*)d_in[12];
  const float* g2       = (const float*)d_in[13];
  const float* beta2    = (const float*)d_in[14];
  const float* w4       = (const float*)d_in[15];
  const float* b4       = (const float*)d_in[16];
  const float* tstep    = (const float*)d_in[17];
  float* out = (float*)d_out;

  char* wsb = (char*)d_ws;
  ushort* o_bf = (ushort*)wsb;                        // 1 MiB
  ushort* w1T  = (ushort*)(wsb + (1<<20));            // 256 KiB
  ushort* w4T  = (ushort*)(wsb + (1<<20) + (256<<10));// 256 KiB
  float*  gacc = (float*)(wsb + (1<<20) + (512<<10)); // 64 B
  float*  cpl  = gacc + 16;                           // 17 floats

  hipLaunchKernelGGL(wn_prep, dim3(129), dim3(256), 0, stream,
                     w1, w4, w1T, w4T, freq, phases, coupling, damping, tstep, cpl, gacc);
  hipLaunchKernelGGL(wn_phase1, dim3(512), dim3(256), 0, stream,
                     x, w1T, b1, g1, beta1, w2, b2, w3, b3, g2, beta2, cpl, o_bf, gacc);
  hipLaunchKernelGGL(wn_phase2, dim3(1), dim3(64), 0, stream, gacc, cpl);
  hipLaunchKernelGGL(wn_phase3, dim3(1024), dim3(256), 0, stream,
                     x, o_bf, w4T, b4, cpl, out);
}

// Round 10
// 185.588 us; speedup vs baseline: 1.0200x; 1.0200x over previous
//
#include <hip/hip_runtime.h>
#include <hip/hip_bf16.h>
#include <math.h>

#define HID 4096
#define R_TOTAL 16384

typedef __attribute__((ext_vector_type(8))) short short8;
typedef __attribute__((ext_vector_type(8))) unsigned short ushort8;
typedef __attribute__((ext_vector_type(4))) float f32x4;

__device__ __forceinline__ ushort bfc(float f) {
  __hip_bfloat16 h = __float2bfloat16(f);
  return *(ushort*)&h;
}

// ---------------------------------------------------------------------------
// Prep: w1T bf16 [32][4096], w4T bf16 [4096][32], coupled[16] -> cpl[0..15],
// gacc zeroing folded in.
// ---------------------------------------------------------------------------
__global__ __launch_bounds__(256) void wn_prep(
    const float* __restrict__ w1, const float* __restrict__ w4,
    ushort* __restrict__ w1T, ushort* __restrict__ w4T,
    const float* __restrict__ freq, const float* __restrict__ phases,
    const float* __restrict__ coupling, const float* __restrict__ damping,
    const float* __restrict__ tstep, float* __restrict__ cpl,
    float* __restrict__ gacc)
{
  __shared__ ushort tile[64*72];
  __shared__ float base[16];
  const int b = blockIdx.x, t = threadIdx.x;
  if (b < 64) {
    #pragma unroll
    for (int i = 0; i < 8; ++i) {
      const int e = t + i*256, kk = e >> 5, c = e & 31;
      tile[c*72 + kk] = bfc(w1[(size_t)(b*64+kk)*32 + c]);
    }
    __syncthreads();
    const int c = t >> 3, j = t & 7;
    ushort8 v;
    #pragma unroll
    for (int q = 0; q < 8; ++q) v[q] = tile[c*72 + j*8 + q];
    *(ushort8*)&w1T[(size_t)c*HID + b*64 + j*8] = v;
  } else if (b < 128) {
    const int b2 = b - 64;
    #pragma unroll
    for (int i = 0; i < 8; ++i) {
      const int e = t + i*256, d = e >> 6, hh = e & 63;
      tile[hh*40 + d] = bfc(w4[(size_t)d*HID + b2*64 + hh]);
    }
    __syncthreads();
    const int hh = t >> 2, j = t & 3;
    ushort8 v;
    #pragma unroll
    for (int q = 0; q < 8; ++q) v[q] = tile[hh*40 + j*8 + q];
    *(ushort8*)&w4T[(size_t)(b2*64+hh)*32 + j*8] = v;
  } else {
    const float tt = tstep[0] + 0.1f;
    if (t < 16) {
      gacc[t] = 0.f;
      base[t] = sinf(6.283185307179586f*freq[t]*tt + phases[t]) * expf(-damping[t]*tt);
    }
    __syncthreads();
    if (t < 16) {
      float s = 0.f;
      #pragma unroll
      for (int i = 0; i < 16; ++i) s += base[i]*coupling[i*16+t];
      cpl[t] = tanhf(s);
    }
  }
}

// ---------------------------------------------------------------------------
// Phase 1 (bf16-LDS MFMA, R8 version): x@w1 -> LN -> SiLU -> @w2 -> mod -> @w3
//   -> LN -> SiLU -> o(bf16).
// ---------------------------------------------------------------------------
__global__ __launch_bounds__(256) void wn_phase1(
    const float* __restrict__ x, const ushort* __restrict__ w1T,
    const float* __restrict__ b1, const float* __restrict__ g1,
    const float* __restrict__ beta1, const float* __restrict__ w2,
    const float* __restrict__ b2, const float* __restrict__ w3,
    const float* __restrict__ b3, const float* __restrict__ g2,
    const float* __restrict__ beta2, const float* __restrict__ cpl,
    ushort* __restrict__ o_ws, float* __restrict__ gacc)
{
  __shared__ __align__(16) float lds[6720];
  ushort* xb  = (ushort*)lds;
  float* red  = lds;
  float* yl   = lds + 4096;
  float* w2l  = lds + 5152;
  float* w3l  = lds + 5664;
  float* msum = lds + 6176;
  const int t  = threadIdx.x;
  const int r0 = blockIdx.x * 32;

  if (t < 128) *(float4*)&w2l[t*4] = *(const float4*)&w2[t*4];
  else { const int u2 = t-128; *(float4*)&w3l[u2*4] = *(const float4*)&w3[u2*4]; }

  const int srow = t >> 3, sc = t & 7;
  const int wg0   = ((sc*2) ^ ((srow&7)<<1));
  const int wbase = srow*128 + wg0*8;
  const float* xp = &x[(size_t)(r0+srow)*HID + sc*16];

  const int w    = t >> 6, l = t & 63;
  const int mt   = w & 1, kh = w >> 1;
  const int lrow = l & 15, lkb = l >> 4;
  const int arow = mt*16 + lrow;
  const int rsw  = (arow&7) << 1;
  const int ra_s0 = arow*128 + ((kh*8 +     lkb) ^ rsw)*8;
  const int ra_s1 = arow*128 + ((kh*8 + 4 + lkb) ^ rsw)*8;
  const ushort* bp0 = &w1T[(size_t)lrow*HID + kh*64 + lkb*8];
  const ushort* bp1 = bp0 + 16*HID;

  f32x4 acc0 = {0.f,0.f,0.f,0.f}, acc1 = {0.f,0.f,0.f,0.f};
  float4 rg0, rg1, rg2, rg3;

  rg0 = *(const float4*)&xp[0];
  rg1 = *(const float4*)&xp[4];
  rg2 = *(const float4*)&xp[8];
  rg3 = *(const float4*)&xp[12];
  {
    ushort8 v0, v1;
    v0[0]=bfc(rg0.x); v0[1]=bfc(rg0.y); v0[2]=bfc(rg0.z); v0[3]=bfc(rg0.w);
    v0[4]=bfc(rg1.x); v0[5]=bfc(rg1.y); v0[6]=bfc(rg1.z); v0[7]=bfc(rg1.w);
    v1[0]=bfc(rg2.x); v1[1]=bfc(rg2.y); v1[2]=bfc(rg2.z); v1[3]=bfc(rg2.w);
    v1[4]=bfc(rg3.x); v1[5]=bfc(rg3.y); v1[6]=bfc(rg3.z); v1[7]=bfc(rg3.w);
    *(ushort8*)&xb[wbase]     = v0;
    *(ushort8*)&xb[wbase + 8] = v1;
  }

  for (int it = 0; it < 32; ++it) {
    const int cur = it & 1;
    if (it < 31) {
      const int kc = (it+1)*128;
      rg0 = *(const float4*)&xp[kc];
      rg1 = *(const float4*)&xp[kc + 4];
      rg2 = *(const float4*)&xp[kc + 8];
      rg3 = *(const float4*)&xp[kc + 12];
    }
    __syncthreads();
    {
      const ushort* xc = &xb[cur*4096];
      const int kg = it*128;
      const short8 av0 = *(const short8*)&xc[ra_s0];
      const short8 bv00 = *(const short8*)(bp0 + kg);
      const short8 bv01 = *(const short8*)(bp1 + kg);
      acc0 = __builtin_amdgcn_mfma_f32_16x16x32_bf16(av0, bv00, acc0, 0, 0, 0);
      acc1 = __builtin_amdgcn_mfma_f32_16x16x32_bf16(av0, bv01, acc1, 0, 0, 0);
      const short8 av1 = *(const short8*)&xc[ra_s1];
      const short8 bv10 = *(const short8*)(bp0 + kg + 32);
      const short8 bv11 = *(const short8*)(bp1 + kg + 32);
      acc0 = __builtin_amdgcn_mfma_f32_16x16x32_bf16(av1, bv10, acc0, 0, 0, 0);
      acc1 = __builtin_amdgcn_mfma_f32_16x16x32_bf16(av1, bv11, acc1, 0, 0, 0);
    }
    __syncthreads();
    if (it < 31) {
      ushort* xn = &xb[(cur^1)*4096];
      ushort8 v0, v1;
      v0[0]=bfc(rg0.x); v0[1]=bfc(rg0.y); v0[2]=bfc(rg0.z); v0[3]=bfc(rg0.w);
      v0[4]=bfc(rg1.x); v0[5]=bfc(rg1.y); v0[6]=bfc(rg1.z); v0[7]=bfc(rg1.w);
      v1[0]=bfc(rg2.x); v1[1]=bfc(rg2.y); v1[2]=bfc(rg2.z); v1[3]=bfc(rg2.w);
      v1[4]=bfc(rg3.x); v1[5]=bfc(rg3.y); v1[6]=bfc(rg3.z); v1[7]=bfc(rg3.w);
      *(ushort8*)&xn[wbase]     = v0;
      *(ushort8*)&xn[wbase + 8] = v1;
    }
  }
  __syncthreads();
  #pragma unroll
  for (int j = 0; j < 4; ++j) {
    red[kh*1056 + (mt*16 + lkb*4 + j)*33 + lrow]      = acc0[j];
    red[kh*1056 + (mt*16 + lkb*4 + j)*33 + 16 + lrow] = acc1[j];
  }
  __syncthreads();
  #pragma unroll
  for (int i = 0; i < 4; ++i) {
    const int e = t + i*256, row = e >> 5, col = e & 31;
    yl[row*33+col] = red[row*33+col] + red[1056 + row*33+col];
  }
  __syncthreads();
  if (t < 128) {
    const int row = t >> 2, q = t & 3, d0 = q*8;
    float v[8]; float mu = 0.f;
    #pragma unroll
    for (int dd = 0; dd < 8; ++dd) { v[dd] = yl[row*33 + d0+dd] + b1[d0+dd]; mu += v[dd]; }
    mu += __shfl_xor(mu,1); mu += __shfl_xor(mu,2); mu *= (1.f/32.f);
    float var = 0.f;
    #pragma unroll
    for (int dd = 0; dd < 8; ++dd) { const float c = v[dd]-mu; var += c*c; }
    var += __shfl_xor(var,1); var += __shfl_xor(var,2);
    const float rs = rsqrtf(var*(1.f/32.f) + 1e-5f);
    float wiv[16];
    #pragma unroll
    for (int ww = 0; ww < 16; ++ww) wiv[ww] = 0.f;
    #pragma unroll
    for (int dd = 0; dd < 8; ++dd) {
      const float hn = (v[dd]-mu)*rs*g1[d0+dd] + beta1[d0+dd];
      const float sl = hn / (1.f + __expf(-hn));
      const float* wr = &w2l[(d0+dd)*16];
      #pragma unroll
      for (int ww = 0; ww < 16; ++ww) wiv[ww] = fmaf(sl, wr[ww], wiv[ww]);
    }
    #pragma unroll
    for (int ww = 0; ww < 16; ++ww) {
      wiv[ww] += __shfl_xor(wiv[ww],1);
      wiv[ww] += __shfl_xor(wiv[ww],2);
    }
    float mod[16];
    #pragma unroll
    for (int ww = 0; ww < 16; ++ww) mod[ww] = cpl[ww]*(1.f + wiv[ww] + b2[ww]);
    #pragma unroll
    for (int j = 0; j < 4; ++j) msum[row*17 + q*4+j] = mod[q*4+j];
    float p[8];
    #pragma unroll
    for (int dd = 0; dd < 8; ++dd) p[dd] = b3[d0+dd];
    #pragma unroll
    for (int ww = 0; ww < 16; ++ww) {
      const float m = mod[ww];
      const float* wr = &w3l[ww*32 + d0];
      #pragma unroll
      for (int dd = 0; dd < 8; ++dd) p[dd] = fmaf(m, wr[dd], p[dd]);
    }
    float mu2 = 0.f;
    #pragma unroll
    for (int dd = 0; dd < 8; ++dd) mu2 += p[dd];
    mu2 += __shfl_xor(mu2,1); mu2 += __shfl_xor(mu2,2); mu2 *= (1.f/32.f);
    float var2 = 0.f;
    #pragma unroll
    for (int dd = 0; dd < 8; ++dd) { const float c = p[dd]-mu2; var2 += c*c; }
    var2 += __shfl_xor(var2,1); var2 += __shfl_xor(var2,2);
    const float rs2 = rsqrtf(var2*(1.f/32.f) + 1e-5f);
    ushort8 ov;
    #pragma unroll
    for (int dd = 0; dd < 8; ++dd) {
      const float hn = (p[dd]-mu2)*rs2*g2[d0+dd] + beta2[d0+dd];
      ov[dd] = bfc(hn / (1.f + __expf(-hn)));
    }
    *(ushort8*)&o_ws[(size_t)(r0+row)*32 + d0] = ov;
  }
  __syncthreads();
  if (t < 16) {
    float s = 0.f;
    for (int r = 0; r < 32; ++r) s += msum[r*17 + t];
    atomicAdd(gacc + t, s);
  }
}

// ---------------------------------------------------------------------------
// Phase 2: resonance_factor -> cpl[16]
// ---------------------------------------------------------------------------
__global__ void wn_phase2(const float* __restrict__ gacc, float* __restrict__ cpl)
{
  __shared__ float res[16];
  const int t = threadIdx.x;
  if (t < 16) res[t] = 0.1f * fabsf(gacc[t] * (1.f/(float)R_TOTAL));
  __syncthreads();
  if (t == 0) {
    float s = 0.f;
    #pragma unroll
    for (int ww = 0; ww < 16; ++ww) s += res[ww];
    cpl[16] = 1.f / (1.f + expf(-s*(1.f/16.f)));
  }
}

// ---------------------------------------------------------------------------
// Phase 3 v6 (explicit 2-deep rotated pipeline, named regs):
// out = x + rf*(o@w4 + b4). R8 structure (1 m-tile/wave, grid 2048, reversed
// rows, nt stores, plain x loads) + software pipeline holding ~6 loads in
// flight per wave: prefetch tiles g+2,g+3 before computing tiles g,g+1.
// ---------------------------------------------------------------------------
__global__ __launch_bounds__(256) void wn_phase3(
    const float* __restrict__ x, const ushort* __restrict__ o_bf,
    const ushort* __restrict__ w4T, const float* __restrict__ b4,
    const float* __restrict__ cpl, float* __restrict__ out)
{
  const int t = threadIdx.x, l = t & 63, w = t >> 6;
  const int bid = blockIdx.x;
  const int strip = bid & 7;
  const int m0 = (255 - (bid >> 3)) * 64 + w*16;   // reversed row order
  const float rf = cpl[16];
  const int lm = l & 15, lkb = l >> 4;
  const short8 bv = *(const short8*)&o_bf[(size_t)(m0+lm)*32 + lkb*8];
  const size_t rowbase = (size_t)(m0+lm)*HID + strip*512 + lkb*4;
  const ushort* wp = &w4T[(size_t)(strip*512 + lm)*32 + lkb*8];
  const float* b4p = &b4[strip*512 + lkb*4];

  // prologue: tiles 0 and 1
  short8 avA = *(const short8*)(wp);
  short8 avB = *(const short8*)(wp + 16*32);
  float4 xvA = *(const float4*)&x[rowbase];
  float4 xvB = *(const float4*)&x[rowbase + 16];
  float4 bqA = *(const float4*)&b4p[0];
  float4 bqB = *(const float4*)&b4p[16];

  for (int g = 0; g < 16; ++g) {
    const int ntA = g*2, ntB = g*2 + 1;
    // prefetch tiles ntA+2, ntB+2 (named regs, issued back-to-back)
    short8 avNA = avA, avNB = avB;
    float4 xvNA = xvA, xvNB = xvB, bqNA = bqA, bqNB = bqB;
    if (g < 15) {
      avNA = *(const short8*)(wp + (size_t)(ntA+2)*16*32);
      avNB = *(const short8*)(wp + (size_t)(ntB+2)*16*32);
      xvNA = *(const float4*)&x[rowbase + (ntA+2)*16];
      xvNB = *(const float4*)&x[rowbase + (ntB+2)*16];
      bqNA = *(const float4*)&b4p[(ntA+2)*16];
      bqNB = *(const float4*)&b4p[(ntB+2)*16];
    }
    // compute + store tile ntA
    f32x4 c0 = {0.f,0.f,0.f,0.f};
    c0 = __builtin_amdgcn_mfma_f32_16x16x32_bf16(avA, bv, c0, 0, 0, 0);
    f32x4 s0;
    s0[0] = fmaf(rf, c0[0] + bqA.x, xvA.x);
    s0[1] = fmaf(rf, c0[1] + bqA.y, xvA.y);
    s0[2] = fmaf(rf, c0[2] + bqA.z, xvA.z);
    s0[3] = fmaf(rf, c0[3] + bqA.w, xvA.w);
    __builtin_nontemporal_store(s0, (f32x4*)&out[rowbase + (size_t)ntA*16]);
    // compute + store tile ntB
    f32x4 c1 = {0.f,0.f,0.f,0.f};
    c1 = __builtin_amdgcn_mfma_f32_16x16x32_bf16(avB, bv, c1, 0, 0, 0);
    f32x4 s1;
    s1[0] = fmaf(rf, c1[0] + bqB.x, xvB.x);
    s1[1] = fmaf(rf, c1[1] + bqB.y, xvB.y);
    s1[2] = fmaf(rf, c1[2] + bqB.z, xvB.z);
    s1[3] = fmaf(rf, c1[3] + bqB.w, xvB.w);
    __builtin_nontemporal_store(s1, (f32x4*)&out[rowbase + (size_t)ntB*16]);
    // rotate
    avA = avNA; avB = avNB; xvA = xvNA; xvB = xvNB; bqA = bqNA; bqB = bqNB;
  }
}

extern "C" void kernel_launch(void* const* d_in, const int* in_sizes, int n_in,
                              void* d_out, int out_size, void* d_ws, size_t ws_size,
                              hipStream_t stream) {
  const float* x        = (const float*)d_in[0];
  const float* freq     = (const float*)d_in[1];
  const float* phases   = (const float*)d_in[2];
  const float* coupling = (const float*)d_in[3];
  const float* damping  = (const float*)d_in[4];
  const float* w1       = (const float*)d_in[5];
  const float* b1       = (const float*)d_in[6];
  const float* g1       = (const float*)d_in[7];
  const float* beta1    = (const float*)d_in[8];
  const float* w2       = (const float*)d_in[9];
  const float* b2       = (const float*)d_in[10];
  const float* w3       = (const float*)d_in[11];
  const float* b3       = (const float*)d_in[12];
  const float* g2       = (const float*)d_in[13];
  const float* beta2    = (const float*)d_in[14];
  const float* w4       = (const float*)d_in[15];
  const float* b4       = (const float*)d_in[16];
  const float* tstep    = (const float*)d_in[17];
  float* out = (float*)d_out;

  char* wsb = (char*)d_ws;
  ushort* o_bf = (ushort*)wsb;                        // 1 MiB
  ushort* w1T  = (ushort*)(wsb + (1<<20));            // 256 KiB
  ushort* w4T  = (ushort*)(wsb + (1<<20) + (256<<10));// 256 KiB
  float*  gacc = (float*)(wsb + (1<<20) + (512<<10)); // 64 B
  float*  cpl  = gacc + 16;                           // 17 floats

  hipLaunchKernelGGL(wn_prep, dim3(129), dim3(256), 0, stream,
                     w1, w4, w1T, w4T, freq, phases, coupling, damping, tstep, cpl, gacc);
  hipLaunchKernelGGL(wn_phase1, dim3(512), dim3(256), 0, stream,
                     x, w1T, b1, g1, beta1, w2, b2, w3, b3, g2, beta2, cpl, o_bf, gacc);
  hipLaunchKernelGGL(wn_phase2, dim3(1), dim3(64), 0, stream, gacc, cpl);
  hipLaunchKernelGGL(wn_phase3, dim3(2048), dim3(256), 0, stream,
                     x, o_bf, w4T, b4, cpl, out);
}

// Round 11
// 175.296 us; speedup vs baseline: 1.0799x; 1.0587x over previous
//
#include <hip/hip_runtime.h>
#include <hip/hip_bf16.h>
#include <math.h>

#define HID 4096
#define R_TOTAL 16384

typedef __attribute__((ext_vector_type(8))) short short8;
typedef __attribute__((ext_vector_type(8))) unsigned short ushort8;
typedef __attribute__((ext_vector_type(4))) float f32x4;

__device__ __forceinline__ ushort bfc(float f) {
  __hip_bfloat16 h = __float2bfloat16(f);
  return *(ushort*)&h;
}

// ---------------------------------------------------------------------------
// Prep: w1T bf16 [32][4096], w4T bf16 [4096][32], coupled[16] -> cpl[0..15],
// gacc zeroing folded in.
// ---------------------------------------------------------------------------
__global__ __launch_bounds__(256) void wn_prep(
    const float* __restrict__ w1, const float* __restrict__ w4,
    ushort* __restrict__ w1T, ushort* __restrict__ w4T,
    const float* __restrict__ freq, const float* __restrict__ phases,
    const float* __restrict__ coupling, const float* __restrict__ damping,
    const float* __restrict__ tstep, float* __restrict__ cpl,
    float* __restrict__ gacc)
{
  __shared__ ushort tile[64*72];
  __shared__ float base[16];
  const int b = blockIdx.x, t = threadIdx.x;
  if (b < 64) {
    #pragma unroll
    for (int i = 0; i < 8; ++i) {
      const int e = t + i*256, kk = e >> 5, c = e & 31;
      tile[c*72 + kk] = bfc(w1[(size_t)(b*64+kk)*32 + c]);
    }
    __syncthreads();
    const int c = t >> 3, j = t & 7;
    ushort8 v;
    #pragma unroll
    for (int q = 0; q < 8; ++q) v[q] = tile[c*72 + j*8 + q];
    *(ushort8*)&w1T[(size_t)c*HID + b*64 + j*8] = v;
  } else if (b < 128) {
    const int b2 = b - 64;
    #pragma unroll
    for (int i = 0; i < 8; ++i) {
      const int e = t + i*256, d = e >> 6, hh = e & 63;
      tile[hh*40 + d] = bfc(w4[(size_t)d*HID + b2*64 + hh]);
    }
    __syncthreads();
    const int hh = t >> 2, j = t & 3;
    ushort8 v;
    #pragma unroll
    for (int q = 0; q < 8; ++q) v[q] = tile[hh*40 + j*8 + q];
    *(ushort8*)&w4T[(size_t)(b2*64+hh)*32 + j*8] = v;
  } else {
    const float tt = tstep[0] + 0.1f;
    if (t < 16) {
      gacc[t] = 0.f;
      base[t] = sinf(6.283185307179586f*freq[t]*tt + phases[t]) * expf(-damping[t]*tt);
    }
    __syncthreads();
    if (t < 16) {
      float s = 0.f;
      #pragma unroll
      for (int i = 0; i < 16; ++i) s += base[i]*coupling[i*16+t];
      cpl[t] = tanhf(s);
    }
  }
}

// ---------------------------------------------------------------------------
// Phase 1 (bf16-LDS MFMA, R8 version): x@w1 -> LN -> SiLU -> @w2 -> mod -> @w3
//   -> LN -> SiLU -> o(bf16).
// ---------------------------------------------------------------------------
__global__ __launch_bounds__(256) void wn_phase1(
    const float* __restrict__ x, const ushort* __restrict__ w1T,
    const float* __restrict__ b1, const float* __restrict__ g1,
    const float* __restrict__ beta1, const float* __restrict__ w2,
    const float* __restrict__ b2, const float* __restrict__ w3,
    const float* __restrict__ b3, const float* __restrict__ g2,
    const float* __restrict__ beta2, const float* __restrict__ cpl,
    ushort* __restrict__ o_ws, float* __restrict__ gacc)
{
  __shared__ __align__(16) float lds[6720];
  ushort* xb  = (ushort*)lds;
  float* red  = lds;
  float* yl   = lds + 4096;
  float* w2l  = lds + 5152;
  float* w3l  = lds + 5664;
  float* msum = lds + 6176;
  const int t  = threadIdx.x;
  const int r0 = blockIdx.x * 32;

  if (t < 128) *(float4*)&w2l[t*4] = *(const float4*)&w2[t*4];
  else { const int u2 = t-128; *(float4*)&w3l[u2*4] = *(const float4*)&w3[u2*4]; }

  const int srow = t >> 3, sc = t & 7;
  const int wg0   = ((sc*2) ^ ((srow&7)<<1));
  const int wbase = srow*128 + wg0*8;
  const float* xp = &x[(size_t)(r0+srow)*HID + sc*16];

  const int w    = t >> 6, l = t & 63;
  const int mt   = w & 1, kh = w >> 1;
  const int lrow = l & 15, lkb = l >> 4;
  const int arow = mt*16 + lrow;
  const int rsw  = (arow&7) << 1;
  const int ra_s0 = arow*128 + ((kh*8 +     lkb) ^ rsw)*8;
  const int ra_s1 = arow*128 + ((kh*8 + 4 + lkb) ^ rsw)*8;
  const ushort* bp0 = &w1T[(size_t)lrow*HID + kh*64 + lkb*8];
  const ushort* bp1 = bp0 + 16*HID;

  f32x4 acc0 = {0.f,0.f,0.f,0.f}, acc1 = {0.f,0.f,0.f,0.f};
  float4 rg0, rg1, rg2, rg3;

  rg0 = *(const float4*)&xp[0];
  rg1 = *(const float4*)&xp[4];
  rg2 = *(const float4*)&xp[8];
  rg3 = *(const float4*)&xp[12];
  {
    ushort8 v0, v1;
    v0[0]=bfc(rg0.x); v0[1]=bfc(rg0.y); v0[2]=bfc(rg0.z); v0[3]=bfc(rg0.w);
    v0[4]=bfc(rg1.x); v0[5]=bfc(rg1.y); v0[6]=bfc(rg1.z); v0[7]=bfc(rg1.w);
    v1[0]=bfc(rg2.x); v1[1]=bfc(rg2.y); v1[2]=bfc(rg2.z); v1[3]=bfc(rg2.w);
    v1[4]=bfc(rg3.x); v1[5]=bfc(rg3.y); v1[6]=bfc(rg3.z); v1[7]=bfc(rg3.w);
    *(ushort8*)&xb[wbase]     = v0;
    *(ushort8*)&xb[wbase + 8] = v1;
  }

  for (int it = 0; it < 32; ++it) {
    const int cur = it & 1;
    if (it < 31) {
      const int kc = (it+1)*128;
      rg0 = *(const float4*)&xp[kc];
      rg1 = *(const float4*)&xp[kc + 4];
      rg2 = *(const float4*)&xp[kc + 8];
      rg3 = *(const float4*)&xp[kc + 12];
    }
    __syncthreads();
    {
      const ushort* xc = &xb[cur*4096];
      const int kg = it*128;
      const short8 av0 = *(const short8*)&xc[ra_s0];
      const short8 bv00 = *(const short8*)(bp0 + kg);
      const short8 bv01 = *(const short8*)(bp1 + kg);
      acc0 = __builtin_amdgcn_mfma_f32_16x16x32_bf16(av0, bv00, acc0, 0, 0, 0);
      acc1 = __builtin_amdgcn_mfma_f32_16x16x32_bf16(av0, bv01, acc1, 0, 0, 0);
      const short8 av1 = *(const short8*)&xc[ra_s1];
      const short8 bv10 = *(const short8*)(bp0 + kg + 32);
      const short8 bv11 = *(const short8*)(bp1 + kg + 32);
      acc0 = __builtin_amdgcn_mfma_f32_16x16x32_bf16(av1, bv10, acc0, 0, 0, 0);
      acc1 = __builtin_amdgcn_mfma_f32_16x16x32_bf16(av1, bv11, acc1, 0, 0, 0);
    }
    __syncthreads();
    if (it < 31) {
      ushort* xn = &xb[(cur^1)*4096];
      ushort8 v0, v1;
      v0[0]=bfc(rg0.x); v0[1]=bfc(rg0.y); v0[2]=bfc(rg0.z); v0[3]=bfc(rg0.w);
      v0[4]=bfc(rg1.x); v0[5]=bfc(rg1.y); v0[6]=bfc(rg1.z); v0[7]=bfc(rg1.w);
      v1[0]=bfc(rg2.x); v1[1]=bfc(rg2.y); v1[2]=bfc(rg2.z); v1[3]=bfc(rg2.w);
      v1[4]=bfc(rg3.x); v1[5]=bfc(rg3.y); v1[6]=bfc(rg3.z); v1[7]=bfc(rg3.w);
      *(ushort8*)&xn[wbase]     = v0;
      *(ushort8*)&xn[wbase + 8] = v1;
    }
  }
  __syncthreads();
  #pragma unroll
  for (int j = 0; j < 4; ++j) {
    red[kh*1056 + (mt*16 + lkb*4 + j)*33 + lrow]      = acc0[j];
    red[kh*1056 + (mt*16 + lkb*4 + j)*33 + 16 + lrow] = acc1[j];
  }
  __syncthreads();
  #pragma unroll
  for (int i = 0; i < 4; ++i) {
    const int e = t + i*256, row = e >> 5, col = e & 31;
    yl[row*33+col] = red[row*33+col] + red[1056 + row*33+col];
  }
  __syncthreads();
  if (t < 128) {
    const int row = t >> 2, q = t & 3, d0 = q*8;
    float v[8]; float mu = 0.f;
    #pragma unroll
    for (int dd = 0; dd < 8; ++dd) { v[dd] = yl[row*33 + d0+dd] + b1[d0+dd]; mu += v[dd]; }
    mu += __shfl_xor(mu,1); mu += __shfl_xor(mu,2); mu *= (1.f/32.f);
    float var = 0.f;
    #pragma unroll
    for (int dd = 0; dd < 8; ++dd) { const float c = v[dd]-mu; var += c*c; }
    var += __shfl_xor(var,1); var += __shfl_xor(var,2);
    const float rs = rsqrtf(var*(1.f/32.f) + 1e-5f);
    float wiv[16];
    #pragma unroll
    for (int ww = 0; ww < 16; ++ww) wiv[ww] = 0.f;
    #pragma unroll
    for (int dd = 0; dd < 8; ++dd) {
      const float hn = (v[dd]-mu)*rs*g1[d0+dd] + beta1[d0+dd];
      const float sl = hn / (1.f + __expf(-hn));
      const float* wr = &w2l[(d0+dd)*16];
      #pragma unroll
      for (int ww = 0; ww < 16; ++ww) wiv[ww] = fmaf(sl, wr[ww], wiv[ww]);
    }
    #pragma unroll
    for (int ww = 0; ww < 16; ++ww) {
      wiv[ww] += __shfl_xor(wiv[ww],1);
      wiv[ww] += __shfl_xor(wiv[ww],2);
    }
    float mod[16];
    #pragma unroll
    for (int ww = 0; ww < 16; ++ww) mod[ww] = cpl[ww]*(1.f + wiv[ww] + b2[ww]);
    #pragma unroll
    for (int j = 0; j < 4; ++j) msum[row*17 + q*4+j] = mod[q*4+j];
    float p[8];
    #pragma unroll
    for (int dd = 0; dd < 8; ++dd) p[dd] = b3[d0+dd];
    #pragma unroll
    for (int ww = 0; ww < 16; ++ww) {
      const float m = mod[ww];
      const float* wr = &w3l[ww*32 + d0];
      #pragma unroll
      for (int dd = 0; dd < 8; ++dd) p[dd] = fmaf(m, wr[dd], p[dd]);
    }
    float mu2 = 0.f;
    #pragma unroll
    for (int dd = 0; dd < 8; ++dd) mu2 += p[dd];
    mu2 += __shfl_xor(mu2,1); mu2 += __shfl_xor(mu2,2); mu2 *= (1.f/32.f);
    float var2 = 0.f;
    #pragma unroll
    for (int dd = 0; dd < 8; ++dd) { const float c = p[dd]-mu2; var2 += c*c; }
    var2 += __shfl_xor(var2,1); var2 += __shfl_xor(var2,2);
    const float rs2 = rsqrtf(var2*(1.f/32.f) + 1e-5f);
    ushort8 ov;
    #pragma unroll
    for (int dd = 0; dd < 8; ++dd) {
      const float hn = (p[dd]-mu2)*rs2*g2[d0+dd] + beta2[d0+dd];
      ov[dd] = bfc(hn / (1.f + __expf(-hn)));
    }
    *(ushort8*)&o_ws[(size_t)(r0+row)*32 + d0] = ov;
  }
  __syncthreads();
  if (t < 16) {
    float s = 0.f;
    for (int r = 0; r < 32; ++r) s += msum[r*17 + t];
    atomicAdd(gacc + t, s);
  }
}

// ---------------------------------------------------------------------------
// Phase 2: resonance_factor -> cpl[16]
// ---------------------------------------------------------------------------
__global__ void wn_phase2(const float* __restrict__ gacc, float* __restrict__ cpl)
{
  __shared__ float res[16];
  const int t = threadIdx.x;
  if (t < 16) res[t] = 0.1f * fabsf(gacc[t] * (1.f/(float)R_TOTAL));
  __syncthreads();
  if (t == 0) {
    float s = 0.f;
    #pragma unroll
    for (int ww = 0; ww < 16; ++ww) s += res[ww];
    cpl[16] = 1.f / (1.f + expf(-s*(1.f/16.f)));
  }
}

// ---------------------------------------------------------------------------
// Phase 3 v7 (LDS-bounce for full-line coalescing):
// out = x + rf*(o@w4 + b4). MFMA C-frags go to a per-wave [16][132] LDS tile;
// epilogue re-reads with 32-lanes-per-row mapping so every x-load/out-store
// instruction covers 2 rows x 512B CONTIGUOUS (full 128B cache lines) instead
// of 16 rows x 64B half-lines. Reversed row order + nt out stores retained.
// 2048 blocks (256 row-blks x 8 strips) x 256 thr (4 waves, 16 rows each).
// ---------------------------------------------------------------------------
__global__ __launch_bounds__(256) void wn_phase3(
    const float* __restrict__ x, const ushort* __restrict__ o_bf,
    const ushort* __restrict__ w4T, const float* __restrict__ b4,
    const float* __restrict__ cpl, float* __restrict__ out)
{
  __shared__ __align__(16) float pl[4][2112];   // per-wave [16 m][132] (pad 4)
  const int t = threadIdx.x, l = t & 63, w = t >> 6;
  const int bid = blockIdx.x;
  const int strip = bid & 7;
  const int m0 = (255 - (bid >> 3)) * 64 + w*16;   // reversed row order
  const float rf = cpl[16];
  const int lm = l & 15, lkb = l >> 4;
  // B-frag: o rows (col operand, m)
  const short8 bv = *(const short8*)&o_bf[(size_t)(m0+lm)*32 + lkb*8];
  float* myl = pl[w];
  const ushort* wp = &w4T[(size_t)(strip*512 + lm)*32 + lkb*8];
  // epilogue mapping: 32 lanes per row, 2 rows per pass
  const int erow = l >> 5;           // 0..1
  const int ecol = (l & 31) * 4;     // float col 0..124

  for (int c = 0; c < 4; ++c) {
    const int h0 = strip*512 + c*128;
    // --- MFMA phase: 8 n-tiles -> LDS tile [16][132] ---
    #pragma unroll
    for (int ntl = 0; ntl < 8; ++ntl) {
      const short8 av = *(const short8*)(wp + (size_t)(c*8 + ntl)*16*32);
      f32x4 cc = {0.f,0.f,0.f,0.f};
      cc = __builtin_amdgcn_mfma_f32_16x16x32_bf16(av, bv, cc, 0, 0, 0);
      // lane holds out[m0+lm][h0 + ntl*16 + lkb*4 + j], j=0..3
      *(f32x4*)&myl[lm*132 + ntl*16 + lkb*4] = cc;
    }
    // --- coalesced epilogue: 8 passes x (2 rows x 512B contiguous) ---
    #pragma unroll
    for (int p = 0; p < 8; ++p) {
      const int r = erow + p*2;                    // m-row within tile
      const size_t off = (size_t)(m0 + r)*HID + h0 + ecol;
      const float4 xv  = *(const float4*)&x[off];
      const f32x4 cv  = *(const f32x4*)&myl[r*132 + ecol];
      const float4 bq  = *(const float4*)&b4[h0 + ecol];
      f32x4 s;
      s[0] = fmaf(rf, cv[0] + bq.x, xv.x);
      s[1] = fmaf(rf, cv[1] + bq.y, xv.y);
      s[2] = fmaf(rf, cv[2] + bq.z, xv.z);
      s[3] = fmaf(rf, cv[3] + bq.w, xv.w);
      __builtin_nontemporal_store(s, (f32x4*)&out[off]);
    }
  }
}

extern "C" void kernel_launch(void* const* d_in, const int* in_sizes, int n_in,
                              void* d_out, int out_size, void* d_ws, size_t ws_size,
                              hipStream_t stream) {
  const float* x        = (const float*)d_in[0];
  const float* freq     = (const float*)d_in[1];
  const float* phases   = (const float*)d_in[2];
  const float* coupling = (const float*)d_in[3];
  const float* damping  = (const float*)d_in[4];
  const float* w1       = (const float*)d_in[5];
  const float* b1       = (const float*)d_in[6];
  const float* g1       = (const float*)d_in[7];
  const float* beta1    = (const float*)d_in[8];
  const float* w2       = (const float*)d_in[9];
  const float* b2       = (const float*)d_in[10];
  const float* w3       = (const float*)d_in[11];
  const float* b3       = (const float*)d_in[12];
  const float* g2       = (const float*)d_in[13];
  const float* beta2    = (const float*)d_in[14];
  const float* w4       = (const float*)d_in[15];
  const float* b4       = (const float*)d_in[16];
  const float* tstep    = (const float*)d_in[17];
  float* out = (float*)d_out;

  char* wsb = (char*)d_ws;
  ushort* o_bf = (ushort*)wsb;                        // 1 MiB
  ushort* w1T  = (ushort*)(wsb + (1<<20));            // 256 KiB
  ushort* w4T  = (ushort*)(wsb + (1<<20) + (256<<10));// 256 KiB
  float*  gacc = (float*)(wsb + (1<<20) + (512<<10)); // 64 B
  float*  cpl  = gacc + 16;                           // 17 floats

  hipLaunchKernelGGL(wn_prep, dim3(129), dim3(256), 0, stream,
                     w1, w4, w1T, w4T, freq, phases, coupling, damping, tstep, cpl, gacc);
  hipLaunchKernelGGL(wn_phase1, dim3(512), dim3(256), 0, stream,
                     x, w1T, b1, g1, beta1, w2, b2, w3, b3, g2, beta2, cpl, o_bf, gacc);
  hipLaunchKernelGGL(wn_phase2, dim3(1), dim3(64), 0, stream, gacc, cpl);
  hipLaunchKernelGGL(wn_phase3, dim3(2048), dim3(256), 0, stream,
                     x, o_bf, w4T, b4, cpl, out);
}

// Round 12
// 168.480 us; speedup vs baseline: 1.1236x; 1.0405x over previous
//
#include <hip/hip_runtime.h>
#include <hip/hip_bf16.h>
#include <math.h>

#define HID 4096
#define R_TOTAL 16384

typedef __attribute__((ext_vector_type(8))) short short8;
typedef __attribute__((ext_vector_type(8))) unsigned short ushort8;
typedef __attribute__((ext_vector_type(4))) float f32x4;

__device__ __forceinline__ ushort bfc(float f) {
  __hip_bfloat16 h = __float2bfloat16(f);
  return *(ushort*)&h;
}

// ---------------------------------------------------------------------------
// Prep: w1T bf16 [32][4096], w4T bf16 [4096][32], coupled[16] -> cpl[0..15],
// gacc zeroing folded in.
// ---------------------------------------------------------------------------
__global__ __launch_bounds__(256) void wn_prep(
    const float* __restrict__ w1, const float* __restrict__ w4,
    ushort* __restrict__ w1T, ushort* __restrict__ w4T,
    const float* __restrict__ freq, const float* __restrict__ phases,
    const float* __restrict__ coupling, const float* __restrict__ damping,
    const float* __restrict__ tstep, float* __restrict__ cpl,
    float* __restrict__ gacc)
{
  __shared__ ushort tile[64*72];
  __shared__ float base[16];
  const int b = blockIdx.x, t = threadIdx.x;
  if (b < 64) {
    #pragma unroll
    for (int i = 0; i < 8; ++i) {
      const int e = t + i*256, kk = e >> 5, c = e & 31;
      tile[c*72 + kk] = bfc(w1[(size_t)(b*64+kk)*32 + c]);
    }
    __syncthreads();
    const int c = t >> 3, j = t & 7;
    ushort8 v;
    #pragma unroll
    for (int q = 0; q < 8; ++q) v[q] = tile[c*72 + j*8 + q];
    *(ushort8*)&w1T[(size_t)c*HID + b*64 + j*8] = v;
  } else if (b < 128) {
    const int b2 = b - 64;
    #pragma unroll
    for (int i = 0; i < 8; ++i) {
      const int e = t + i*256, d = e >> 6, hh = e & 63;
      tile[hh*40 + d] = bfc(w4[(size_t)d*HID + b2*64 + hh]);
    }
    __syncthreads();
    const int hh = t >> 2, j = t & 3;
    ushort8 v;
    #pragma unroll
    for (int q = 0; q < 8; ++q) v[q] = tile[hh*40 + j*8 + q];
    *(ushort8*)&w4T[(size_t)(b2*64+hh)*32 + j*8] = v;
  } else {
    const float tt = tstep[0] + 0.1f;
    if (t < 16) {
      gacc[t] = 0.f;
      base[t] = sinf(6.283185307179586f*freq[t]*tt + phases[t]) * expf(-damping[t]*tt);
    }
    __syncthreads();
    if (t < 16) {
      float s = 0.f;
      #pragma unroll
      for (int i = 0; i < 16; ++i) s += base[i]*coupling[i*16+t];
      cpl[t] = tanhf(s);
    }
  }
}

// ---------------------------------------------------------------------------
// Phase 1 v4 (16 rows/block, 4-way split-K, 4 blocks/CU):
// x@w1 -> LN -> SiLU -> @w2 -> mod -> @w3 -> LN -> SiLU -> o(bf16).
// 1024 blocks x 256 thr (4 waves). Each wave owns one 32-k quarter of each
// 128-k chunk (2 MFMAs/chunk). bf16-at-staging, XOR-swizzled LDS, dbuf.
// LDS ~15.5KB -> 4 blocks/CU, 16 waves/CU (2x R8's wave parallelism).
// ---------------------------------------------------------------------------
__global__ __launch_bounds__(256) void wn_phase1(
    const float* __restrict__ x, const ushort* __restrict__ w1T,
    const float* __restrict__ b1, const float* __restrict__ g1,
    const float* __restrict__ beta1, const float* __restrict__ w2,
    const float* __restrict__ b2, const float* __restrict__ w3,
    const float* __restrict__ b3, const float* __restrict__ g2,
    const float* __restrict__ beta2, const float* __restrict__ cpl,
    ushort* __restrict__ o_ws, float* __restrict__ gacc)
{
  __shared__ __align__(16) float lds[3872];
  ushort* xb  = (ushort*)lds;      // 2 x [16 rows][128 k] bf16 (8KB)
  float* red  = lds;               // overlay after K-loop: [4][512] = 2048
  float* yl   = lds + 2048;        // [16][33] = 528
  float* w2l  = lds + 2576;        // [32][16] = 512
  float* w3l  = lds + 3088;        // [16][32] = 512
  float* msum = lds + 3600;        // [16][17] = 272
  const int t  = threadIdx.x;
  const int r0 = blockIdx.x * 16;

  if (t < 128) *(float4*)&w2l[t*4] = *(const float4*)&w2[t*4];
  else { const int u2 = t-128; *(float4*)&w3l[u2*4] = *(const float4*)&w3[u2*4]; }

  // staging: thread -> (row, 8-float piece)
  const int srow = t >> 4, su = t & 15;
  const int pg    = su ^ ((srow & 7) << 1);       // swizzled granule
  const int wbase = srow*128 + pg*8;              // ushort offset within buffer
  const float* xp = &x[(size_t)(r0+srow)*HID + su*8];

  // MFMA mapping: wave kh = K-quarter
  const int kh = t >> 6, l = t & 63;
  const int lrow = l & 15, lkb = l >> 4;
  const int g    = kh*4 + lkb;
  const int ra   = lrow*128 + (g ^ ((lrow & 7) << 1))*8;
  const ushort* bp0 = &w1T[(size_t)lrow*HID + kh*32 + lkb*8];
  const ushort* bp1 = bp0 + 16*HID;

  f32x4 acc0 = {0.f,0.f,0.f,0.f}, acc1 = {0.f,0.f,0.f,0.f};
  float4 rg0, rg1;

  rg0 = *(const float4*)&xp[0];
  rg1 = *(const float4*)&xp[4];
  {
    ushort8 v0;
    v0[0]=bfc(rg0.x); v0[1]=bfc(rg0.y); v0[2]=bfc(rg0.z); v0[3]=bfc(rg0.w);
    v0[4]=bfc(rg1.x); v0[5]=bfc(rg1.y); v0[6]=bfc(rg1.z); v0[7]=bfc(rg1.w);
    *(ushort8*)&xb[wbase] = v0;
  }

  for (int it = 0; it < 32; ++it) {
    const int cur = it & 1;
    if (it < 31) {
      const int kc = (it+1)*128;
      rg0 = *(const float4*)&xp[kc];
      rg1 = *(const float4*)&xp[kc + 4];
    }
    __syncthreads();
    {
      const ushort* xc = &xb[cur*2048];
      const int kg = it*128;
      const short8 av  = *(const short8*)&xc[ra];
      const short8 bv0 = *(const short8*)(bp0 + kg);
      const short8 bv1 = *(const short8*)(bp1 + kg);
      acc0 = __builtin_amdgcn_mfma_f32_16x16x32_bf16(av, bv0, acc0, 0, 0, 0);
      acc1 = __builtin_amdgcn_mfma_f32_16x16x32_bf16(av, bv1, acc1, 0, 0, 0);
    }
    __syncthreads();
    if (it < 31) {
      ushort* xn = &xb[(cur^1)*2048];
      ushort8 v0;
      v0[0]=bfc(rg0.x); v0[1]=bfc(rg0.y); v0[2]=bfc(rg0.z); v0[3]=bfc(rg0.w);
      v0[4]=bfc(rg1.x); v0[5]=bfc(rg1.y); v0[6]=bfc(rg1.z); v0[7]=bfc(rg1.w);
      *(ushort8*)&xn[wbase] = v0;
    }
  }
  __syncthreads();
  // write split-K partials: lane l holds C[row=lkb*4+j][col=lrow (+16)]
  {
    float* rp = &red[kh*512 + l];
    #pragma unroll
    for (int j = 0; j < 4; ++j) { rp[j*64] = acc0[j]; rp[(4+j)*64] = acc1[j]; }
  }
  __syncthreads();
  if (t < 64) {   // reduce 4 K-quarters -> yl[16][33]
    const int rr = (t >> 4)*4, cc = t & 15;
    #pragma unroll
    for (int j = 0; j < 4; ++j) {
      float s0 = 0.f, s1 = 0.f;
      #pragma unroll
      for (int k = 0; k < 4; ++k) {
        s0 += red[k*512 + j*64 + t];
        s1 += red[k*512 + (4+j)*64 + t];
      }
      yl[(rr+j)*33 + cc]      = s0;
      yl[(rr+j)*33 + 16 + cc] = s1;
    }
  }
  __syncthreads();
  // fused epilogue: 4 threads/row (16 rows)
  if (t < 64) {
    const int row = t >> 2, q = t & 3, d0 = q*8;
    float v[8]; float mu = 0.f;
    #pragma unroll
    for (int dd = 0; dd < 8; ++dd) { v[dd] = yl[row*33 + d0+dd] + b1[d0+dd]; mu += v[dd]; }
    mu += __shfl_xor(mu,1); mu += __shfl_xor(mu,2); mu *= (1.f/32.f);
    float var = 0.f;
    #pragma unroll
    for (int dd = 0; dd < 8; ++dd) { const float c = v[dd]-mu; var += c*c; }
    var += __shfl_xor(var,1); var += __shfl_xor(var,2);
    const float rs = rsqrtf(var*(1.f/32.f) + 1e-5f);
    float wiv[16];
    #pragma unroll
    for (int ww = 0; ww < 16; ++ww) wiv[ww] = 0.f;
    #pragma unroll
    for (int dd = 0; dd < 8; ++dd) {
      const float hn = (v[dd]-mu)*rs*g1[d0+dd] + beta1[d0+dd];
      const float sl = hn / (1.f + __expf(-hn));
      const float* wr = &w2l[(d0+dd)*16];
      #pragma unroll
      for (int ww = 0; ww < 16; ++ww) wiv[ww] = fmaf(sl, wr[ww], wiv[ww]);
    }
    #pragma unroll
    for (int ww = 0; ww < 16; ++ww) {
      wiv[ww] += __shfl_xor(wiv[ww],1);
      wiv[ww] += __shfl_xor(wiv[ww],2);
    }
    float mod[16];
    #pragma unroll
    for (int ww = 0; ww < 16; ++ww) mod[ww] = cpl[ww]*(1.f + wiv[ww] + b2[ww]);
    #pragma unroll
    for (int j = 0; j < 4; ++j) msum[row*17 + q*4+j] = mod[q*4+j];
    float p[8];
    #pragma unroll
    for (int dd = 0; dd < 8; ++dd) p[dd] = b3[d0+dd];
    #pragma unroll
    for (int ww = 0; ww < 16; ++ww) {
      const float m = mod[ww];
      const float* wr = &w3l[ww*32 + d0];
      #pragma unroll
      for (int dd = 0; dd < 8; ++dd) p[dd] = fmaf(m, wr[dd], p[dd]);
    }
    float mu2 = 0.f;
    #pragma unroll
    for (int dd = 0; dd < 8; ++dd) mu2 += p[dd];
    mu2 += __shfl_xor(mu2,1); mu2 += __shfl_xor(mu2,2); mu2 *= (1.f/32.f);
    float var2 = 0.f;
    #pragma unroll
    for (int dd = 0; dd < 8; ++dd) { const float c = p[dd]-mu2; var2 += c*c; }
    var2 += __shfl_xor(var2,1); var2 += __shfl_xor(var2,2);
    const float rs2 = rsqrtf(var2*(1.f/32.f) + 1e-5f);
    ushort8 ov;
    #pragma unroll
    for (int dd = 0; dd < 8; ++dd) {
      const float hn = (p[dd]-mu2)*rs2*g2[d0+dd] + beta2[d0+dd];
      ov[dd] = bfc(hn / (1.f + __expf(-hn)));
    }
    *(ushort8*)&o_ws[(size_t)(r0+row)*32 + d0] = ov;
  }
  __syncthreads();
  if (t < 16) {
    float s = 0.f;
    for (int r = 0; r < 16; ++r) s += msum[r*17 + t];
    atomicAdd(gacc + t, s);
  }
}

// ---------------------------------------------------------------------------
// Phase 2: resonance_factor -> cpl[16]
// ---------------------------------------------------------------------------
__global__ void wn_phase2(const float* __restrict__ gacc, float* __restrict__ cpl)
{
  __shared__ float res[16];
  const int t = threadIdx.x;
  if (t < 16) res[t] = 0.1f * fabsf(gacc[t] * (1.f/(float)R_TOTAL));
  __syncthreads();
  if (t == 0) {
    float s = 0.f;
    #pragma unroll
    for (int ww = 0; ww < 16; ++ww) s += res[ww];
    cpl[16] = 1.f / (1.f + expf(-s*(1.f/16.f)));
  }
}

// ---------------------------------------------------------------------------
// Phase 3 v7 (LDS-bounce, R11 version — best): out = x + rf*(o@w4 + b4).
// ---------------------------------------------------------------------------
__global__ __launch_bounds__(256) void wn_phase3(
    const float* __restrict__ x, const ushort* __restrict__ o_bf,
    const ushort* __restrict__ w4T, const float* __restrict__ b4,
    const float* __restrict__ cpl, float* __restrict__ out)
{
  __shared__ __align__(16) float pl[4][2112];   // per-wave [16 m][132]
  const int t = threadIdx.x, l = t & 63, w = t >> 6;
  const int bid = blockIdx.x;
  const int strip = bid & 7;
  const int m0 = (255 - (bid >> 3)) * 64 + w*16;   // reversed row order
  const float rf = cpl[16];
  const int lm = l & 15, lkb = l >> 4;
  const short8 bv = *(const short8*)&o_bf[(size_t)(m0+lm)*32 + lkb*8];
  float* myl = pl[w];
  const ushort* wp = &w4T[(size_t)(strip*512 + lm)*32 + lkb*8];
  const int erow = l >> 5;
  const int ecol = (l & 31) * 4;

  for (int c = 0; c < 4; ++c) {
    const int h0 = strip*512 + c*128;
    #pragma unroll
    for (int ntl = 0; ntl < 8; ++ntl) {
      const short8 av = *(const short8*)(wp + (size_t)(c*8 + ntl)*16*32);
      f32x4 cc = {0.f,0.f,0.f,0.f};
      cc = __builtin_amdgcn_mfma_f32_16x16x32_bf16(av, bv, cc, 0, 0, 0);
      *(f32x4*)&myl[lm*132 + ntl*16 + lkb*4] = cc;
    }
    #pragma unroll
    for (int p = 0; p < 8; ++p) {
      const int r = erow + p*2;
      const size_t off = (size_t)(m0 + r)*HID + h0 + ecol;
      const float4 xv  = *(const float4*)&x[off];
      const f32x4 cv  = *(const f32x4*)&myl[r*132 + ecol];
      const float4 bq  = *(const float4*)&b4[h0 + ecol];
      f32x4 s;
      s[0] = fmaf(rf, cv[0] + bq.x, xv.x);
      s[1] = fmaf(rf, cv[1] + bq.y, xv.y);
      s[2] = fmaf(rf, cv[2] + bq.z, xv.z);
      s[3] = fmaf(rf, cv[3] + bq.w, xv.w);
      __builtin_nontemporal_store(s, (f32x4*)&out[off]);
    }
  }
}

extern "C" void kernel_launch(void* const* d_in, const int* in_sizes, int n_in,
                              void* d_out, int out_size, void* d_ws, size_t ws_size,
                              hipStream_t stream) {
  const float* x        = (const float*)d_in[0];
  const float* freq     = (const float*)d_in[1];
  const float* phases   = (const float*)d_in[2];
  const float* coupling = (const float*)d_in[3];
  const float* damping  = (const float*)d_in[4];
  const float* w1       = (const float*)d_in[5];
  const float* b1       = (const float*)d_in[6];
  const float* g1       = (const float*)d_in[7];
  const float* beta1    = (const float*)d_in[8];
  const float* w2       = (const float*)d_in[9];
  const float* b2       = (const float*)d_in[10];
  const float* w3       = (const float*)d_in[11];
  const float* b3       = (const float*)d_in[12];
  const float* g2       = (const float*)d_in[13];
  const float* beta2    = (const float*)d_in[14];
  const float* w4       = (const float*)d_in[15];
  const float* b4       = (const float*)d_in[16];
  const float* tstep    = (const float*)d_in[17];
  float* out = (float*)d_out;

  char* wsb = (char*)d_ws;
  ushort* o_bf = (ushort*)wsb;                        // 1 MiB
  ushort* w1T  = (ushort*)(wsb + (1<<20));            // 256 KiB
  ushort* w4T  = (ushort*)(wsb + (1<<20) + (256<<10));// 256 KiB
  float*  gacc = (float*)(wsb + (1<<20) + (512<<10)); // 64 B
  float*  cpl  = gacc + 16;                           // 17 floats

  hipLaunchKernelGGL(wn_prep, dim3(129), dim3(256), 0, stream,
                     w1, w4, w1T, w4T, freq, phases, coupling, damping, tstep, cpl, gacc);
  hipLaunchKernelGGL(wn_phase1, dim3(1024), dim3(256), 0, stream,
                     x, w1T, b1, g1, beta1, w2, b2, w3, b3, g2, beta2, cpl, o_bf, gacc);
  hipLaunchKernelGGL(wn_phase2, dim3(1), dim3(64), 0, stream, gacc, cpl);
  hipLaunchKernelGGL(wn_phase3, dim3(2048), dim3(256), 0, stream,
                     x, o_bf, w4T, b4, cpl, out);
}